// Round 3
// baseline (343.252 us; speedup 1.0000x reference)
//
#include <hip/hip_runtime.h>

// ---------------------------------------------------------------------------
// 2-layer GCN forward, pull-mode, bf16 tables, MFMA GEMMs.
//
// R10 (resubmit x2 — R1/R2 benches lost to GPUAcquisitionTimeout):
// feature-sliced phase gather. Gather tables stored slice-major
// [D/16][N][16] so one 16-feature slice of all N rows = 3.2MB fits a per-XCD
// L2 (4MB). Gather grid is all-resident (1563 blocks x 128 thr ~ 6/CU) and
// loops slices OUTERMOST -> whole GPU sweeps slice s in loose lockstep ->
// per-XCD L2 serves most edge reads (was: random 256B rows from a 25.6MB
// table, ~66% HBM miss at 3.7 TB/s, MLP already saturated 6x -> rate was the
// wall, locality is the fix).  Lane-pair owns one node (no shuffle reduce,
// no masked dummy slots); block's edge list staged once in 8KB LDS, reused
// across slices.  GEMM epilogues emit slice-major; gemm2 A-reads remapped
// (fragments stay within a slice -> still single 16B loads).
//
// ws (4B units): dinv[Np] rowptr[Np+4] counts[MAXBK*NB] bsum[128]
//   csr_src[E] tmpP[E] | h ushort[N*128] (reused as h2) | h1 ushort[N*128]
// ---------------------------------------------------------------------------

typedef unsigned int uint;
typedef unsigned short ushort;
typedef __attribute__((ext_vector_type(8))) short bf16x8;
typedef __attribute__((ext_vector_type(8))) ushort u16x8;
typedef __attribute__((ext_vector_type(4))) float f32x4;

#define BSHIFT 8          // nodes per bucket = 256
#define MAXBK  512        // max buckets (N <= 131072)
#define NB     256        // hist/scatter blocks
#define CAP    8192       // LDS-staged edges per bucket (avg ~4096)

__device__ inline ushort f2bf(float f) {
    uint u = __float_as_uint(f);
    return (ushort)((u + 0x7fffu + ((u >> 16) & 1u)) >> 16);  // RNE
}
__device__ inline float bf_lo(uint u) { return __uint_as_float(u << 16); }
__device__ inline float bf_hi(uint u) { return __uint_as_float(u & 0xffff0000u); }

// ---- pass 1: per-block bucket histogram (LDS atomics only) ----
__global__ __launch_bounds__(256) void hist_kernel(const int* __restrict__ tgt,
                                                   int* __restrict__ counts,
                                                   int E, int chunk, int nbk) {
    __shared__ int hist[MAXBK];
    int t = threadIdx.x, b = blockIdx.x;
    for (int i = t; i < nbk; i += 256) hist[i] = 0;
    __syncthreads();
    int s = b * chunk, e = min(E, s + chunk);
    int i = s + t * 4;
    for (; i + 3 < e; i += 1024) {
        int4 tv = *(const int4*)&tgt[i];
        atomicAdd(&hist[tv.x >> BSHIFT], 1);
        atomicAdd(&hist[tv.y >> BSHIFT], 1);
        atomicAdd(&hist[tv.z >> BSHIFT], 1);
        atomicAdd(&hist[tv.w >> BSHIFT], 1);
    }
    if (i < e)
        for (int k = i; k < e; ++k) atomicAdd(&hist[tgt[k] >> BSHIFT], 1);
    __syncthreads();
    for (int i2 = t; i2 < nbk; i2 += 256) counts[i2 * NB + b] = hist[i2];
}

// ---- scan step 1: per-1024 partial sums of counts ----
__global__ __launch_bounds__(256) void scan_partial(const int* __restrict__ in,
                                                    int* __restrict__ bsum, int M) {
    int t = threadIdx.x, b = blockIdx.x;
    int base = b * 1024 + t * 4;
    int s = 0;
#pragma unroll
    for (int k = 0; k < 4; ++k) s += (base + k < M) ? in[base + k] : 0;
#pragma unroll
    for (int off = 32; off > 0; off >>= 1) s += __shfl_down(s, off, 64);
    __shared__ int ws[4];
    if ((t & 63) == 0) ws[t >> 6] = s;
    __syncthreads();
    if (t == 0) bsum[b] = ws[0] + ws[1] + ws[2] + ws[3];
}

// ---- scan step 2: exclusive scan of counts in place (bsum prefix fused) ----
__global__ __launch_bounds__(256) void scan_final_counts(int* __restrict__ counts,
                                                         const int* __restrict__ bsum,
                                                         int M) {
    int t = threadIdx.x, b = blockIdx.x;
    int lane = t & 63, wid = t >> 6;
    int p = 0;
    for (int i = t; i < b; i += 256) p += bsum[i];
#pragma unroll
    for (int off = 32; off > 0; off >>= 1) p += __shfl_down(p, off, 64);
    __shared__ int ps[4];
    if (lane == 0) ps[wid] = p;
    __syncthreads();
    int pre = ps[0] + ps[1] + ps[2] + ps[3];

    int base = b * 1024 + t * 4;
    int d[4];
#pragma unroll
    for (int k = 0; k < 4; ++k) d[k] = (base + k < M) ? counts[base + k] : 0;
    int tot = d[0] + d[1] + d[2] + d[3];
    int incl = tot;
#pragma unroll
    for (int off = 1; off < 64; off <<= 1) {
        int u = __shfl_up(incl, off, 64);
        if (lane >= off) incl += u;
    }
    __shared__ int wsum[4];
    if (lane == 63) wsum[wid] = incl;
    __syncthreads();
    int woff = 0;
    for (int w = 0; w < wid; ++w) woff += wsum[w];
    int run = incl - tot + woff + pre;
#pragma unroll
    for (int k = 0; k < 4; ++k) {
        if (base + k < M) counts[base + k] = run;
        run += d[k];
    }
}

// ---- pass 2: scatter edges into bucket-contiguous packed tmp ----
__global__ __launch_bounds__(256) void bucket_scatter(const int* __restrict__ src,
                                                      const int* __restrict__ tgt,
                                                      const int* __restrict__ offsets,
                                                      int* __restrict__ tmpP,
                                                      int E, int chunk, int nbk) {
    __shared__ int cur[MAXBK];
    int t = threadIdx.x, b = blockIdx.x;
    for (int i = t; i < nbk; i += 256) cur[i] = offsets[i * NB + b];
    __syncthreads();
    int s = b * chunk, e = min(E, s + chunk);
    int i = s + t * 4;
    for (; i + 3 < e; i += 1024) {
        int4 sv = *(const int4*)&src[i];
        int4 tv = *(const int4*)&tgt[i];
        int p0 = atomicAdd(&cur[tv.x >> BSHIFT], 1);
        tmpP[p0] = (sv.x << BSHIFT) | (tv.x & 255);
        int p1 = atomicAdd(&cur[tv.y >> BSHIFT], 1);
        tmpP[p1] = (sv.y << BSHIFT) | (tv.y & 255);
        int p2 = atomicAdd(&cur[tv.z >> BSHIFT], 1);
        tmpP[p2] = (sv.z << BSHIFT) | (tv.z & 255);
        int p3 = atomicAdd(&cur[tv.w >> BSHIFT], 1);
        tmpP[p3] = (sv.w << BSHIFT) | (tv.w & 255);
    }
    if (i < e) {
        for (int k = i; k < e; ++k) {
            int tg = tgt[k];
            int p = atomicAdd(&cur[tg >> BSHIFT], 1);
            tmpP[p] = (src[k] << BSHIFT) | (tg & 255);
        }
    }
}

// ---- pass 3 (fused): per-bucket deg count + scan + rowptr/dinv + csr fill ----
__global__ __launch_bounds__(256) void bucket_finish(const int* __restrict__ tmpP,
                                                     const int* __restrict__ offsets,
                                                     int* __restrict__ rowptr,
                                                     float* __restrict__ dinv,
                                                     int* __restrict__ csr_src,
                                                     int N, int E, int nbk) {
    __shared__ int stage[CAP];
    __shared__ int cnt[256];
    __shared__ int wsum[4];
    int t = threadIdx.x, b = blockIdx.x;
    cnt[t] = 0;
    __syncthreads();
    int s = offsets[b * NB];
    int e = (b + 1 < nbk) ? offsets[(b + 1) * NB] : E;
    int m = e - s;
    for (int i = t; i < m; i += 256) {
        int ed = tmpP[s + i];
        if (i < CAP) stage[i] = ed;
        atomicAdd(&cnt[ed & 255], 1);
    }
    __syncthreads();
    int lane = t & 63, wid = t >> 6;
    int d = cnt[t];
    int incl = d;
#pragma unroll
    for (int off = 1; off < 64; off <<= 1) {
        int u = __shfl_up(incl, off, 64);
        if (lane >= off) incl += u;
    }
    if (lane == 63) wsum[wid] = incl;
    __syncthreads();
    int woff = 0;
    for (int w = 0; w < wid; ++w) woff += wsum[w];
    int excl = s + incl - d + woff;
    int node = b * 256 + t;
    if (node < N) {
        rowptr[node] = excl;
        dinv[node] = rsqrtf((float)d + 1.0f);  // +1 self-loop
    }
    if (b == nbk - 1 && t == 255) rowptr[N] = E;
    cnt[t] = excl;  // reuse as cursor
    __syncthreads();
    for (int i = t; i < m; i += 256) {
        int ed = (i < CAP) ? stage[i] : tmpP[s + i];
        int p = atomicAdd(&cnt[ed & 255], 1);
        csr_src[p] = ed >> BSHIFT;
    }
}

// ---- MFMA GEMM: C(slice-major [M/16][N][16], bf16) = dinv[row]*(A @ W) ----
// block = 256 (4 waves), 64 rows/block; v_mfma_f32_16x16x32_bf16.
// AT = float: A row-major [N][128] fp32 (convert in flight).
// AT = ushort: A slice-major [128/16][N][16] bf16 (gather-table layout).
template <int M, typename AT>
__global__ __launch_bounds__(256) void gemm_mfma(const AT* __restrict__ A,
                                                 const float* __restrict__ W,
                                                 const float* __restrict__ dinv,
                                                 ushort* __restrict__ C, int N) {
    constexpr int WTS = 136;           // padded row stride (bf16)
    __shared__ ushort WT[M * WTS];     // WT[n][k] = W[k][n]
    const int tid = threadIdx.x;
    for (int i = tid; i < 128 * (M / 4); i += 256) {
        int k = i / (M / 4);
        int n0 = (i % (M / 4)) * 4;
        float4 w = *(const float4*)&W[k * M + n0];
        WT[(n0 + 0) * WTS + k] = f2bf(w.x);
        WT[(n0 + 1) * WTS + k] = f2bf(w.y);
        WT[(n0 + 2) * WTS + k] = f2bf(w.z);
        WT[(n0 + 3) * WTS + k] = f2bf(w.w);
    }
    __syncthreads();

    const int wv = tid >> 6, lane = tid & 63;
    const int quad = lane >> 4, mrow = lane & 15;
    int arow_i = blockIdx.x * 64 + wv * 16 + mrow;
    if (arow_i >= N) arow_i = N - 1;   // clamp loads; stores guarded

    f32x4 acc[M / 16];
#pragma unroll
    for (int t = 0; t < M / 16; ++t) acc[t] = (f32x4){0.f, 0.f, 0.f, 0.f};

#pragma unroll
    for (int ks = 0; ks < 4; ++ks) {
        const int k0 = ks * 32 + quad * 8;
        bf16x8 af;
        if constexpr (sizeof(AT) == 4) {
            const float* arow = (const float*)A + (size_t)arow_i * 128;
            float4 a0 = *(const float4*)&arow[k0];
            float4 a1 = *(const float4*)&arow[k0 + 4];
            af[0] = (short)f2bf(a0.x); af[1] = (short)f2bf(a0.y);
            af[2] = (short)f2bf(a0.z); af[3] = (short)f2bf(a0.w);
            af[4] = (short)f2bf(a1.x); af[5] = (short)f2bf(a1.y);
            af[6] = (short)f2bf(a1.z); af[7] = (short)f2bf(a1.w);
        } else {
            // slice-major: features k0..k0+7 live in slice k0>>4 at offset k0&15
            af = *(const bf16x8*)((const ushort*)A +
                                  ((size_t)(k0 >> 4) * N + arow_i) * 16 + (k0 & 15));
        }
#pragma unroll
        for (int t = 0; t < M / 16; ++t) {
            int n = t * 16 + mrow;
            bf16x8 bfr = *(const bf16x8*)&WT[n * WTS + k0];
            acc[t] = __builtin_amdgcn_mfma_f32_16x16x32_bf16(af, bfr, acc[t], 0, 0, 0);
        }
    }

    const int orow0 = blockIdx.x * 64 + wv * 16 + quad * 4;
#pragma unroll
    for (int r = 0; r < 4; ++r) {
        int orow = orow0 + r;
        if (orow < N) {
            float dv = dinv[orow];   // pre-scale row into the gather table
#pragma unroll
            for (int t = 0; t < M / 16; ++t)
                C[((size_t)t * N + orow) * 16 + mrow] = f2bf(dv * acc[t][r]);
        }
    }
}

// ---- feature-sliced phase gather ----
// h slice-major [D/16][N][16] bf16 (pre-scaled by dinv[src]).  Block = 128
// threads = 64 nodes, lane-PAIR per node (q = lane&1 covers 8 features).
// Slice loop is OUTERMOST: the (all-resident) grid sweeps one 3.2MB slice at
// a time -> per-XCD L2 residency.  Block's edge list staged once in LDS.
// out[v] = dinv[v]*(sum_e h'[src] + h'[v]) + b
template <int D, bool RELU, bool OUTBF>
__global__ __launch_bounds__(128) void gather_sliced(
    const ushort* __restrict__ h, const int* __restrict__ rowptr,
    const int* __restrict__ csr_src, const float* __restrict__ dinv,
    const float* __restrict__ bias, void* __restrict__ outv, int N) {
    constexpr int NS = D / 16;     // slices
    constexpr int CAPE = 2048;     // LDS-staged edges per block (avg ~1024)
    __shared__ int eL[CAPE];
    const int tid = threadIdx.x;
    const int base = blockIdx.x * 64;
    const int bbeg = rowptr[base];
    const int bend = rowptr[min(base + 64, N)];
    const int m = bend - bbeg;
    for (int i = tid; i < m && i < CAPE; i += 128) eL[i] = csr_src[bbeg + i];
    __syncthreads();

    const int node = base + (tid >> 1);
    const int q = tid & 1;
    const int qoff = q * 8;
    const bool alive = node < N;
    int beg = 0, end = 0;
    float di = 0.f;
    if (alive) {
        beg = rowptr[node];
        end = rowptr[node + 1];
        di = dinv[node];
    }

    auto acc8 = [](float* a, uint4 v) {
        a[0] += bf_lo(v.x); a[1] += bf_hi(v.x);
        a[2] += bf_lo(v.y); a[3] += bf_hi(v.y);
        a[4] += bf_lo(v.z); a[5] += bf_hi(v.z);
        a[6] += bf_lo(v.w); a[7] += bf_hi(v.w);
    };

    auto run = [&](auto LD) {
#pragma unroll 1
        for (int s = 0; s < NS; ++s) {
            const ushort* hs = h + (size_t)s * N * 16;
            float acc[8] = {};
            if (alive) {
                int j = beg;
                for (; j + 1 < end; j += 2) {     // 2 independent loads in flight
                    int s0 = LD(j), s1 = LD(j + 1);
                    uint4 va = *(const uint4*)&hs[(size_t)s0 * 16 + qoff];
                    uint4 vb = *(const uint4*)&hs[(size_t)s1 * 16 + qoff];
                    acc8(acc, va);
                    acc8(acc, vb);
                }
                if (j < end) {
                    int s0 = LD(j);
                    acc8(acc, *(const uint4*)&hs[(size_t)s0 * 16 + qoff]);
                }
                // self-loop: + h'[node]
                acc8(acc, *(const uint4*)&hs[(size_t)node * 16 + qoff]);

                float4 b0 = *(const float4*)&bias[s * 16 + qoff];
                float4 b1 = *(const float4*)&bias[s * 16 + qoff + 4];
                float r[8] = {di * acc[0] + b0.x, di * acc[1] + b0.y,
                              di * acc[2] + b0.z, di * acc[3] + b0.w,
                              di * acc[4] + b1.x, di * acc[5] + b1.y,
                              di * acc[6] + b1.z, di * acc[7] + b1.w};
                if (RELU) {
#pragma unroll
                    for (int k = 0; k < 8; ++k) r[k] = fmaxf(r[k], 0.0f);
                }
                if constexpr (OUTBF) {
                    ushort* out = (ushort*)outv;   // slice-major bf16
                    u16x8 o;
#pragma unroll
                    for (int k = 0; k < 8; ++k) o[k] = f2bf(r[k]);
                    *(u16x8*)&out[((size_t)s * N + node) * 16 + qoff] = o;
                } else {
                    float* out = (float*)outv;     // row-major fp32
                    *(float4*)&out[(size_t)node * D + s * 16 + qoff] =
                        make_float4(r[0], r[1], r[2], r[3]);
                    *(float4*)&out[(size_t)node * D + s * 16 + qoff + 4] =
                        make_float4(r[4], r[5], r[6], r[7]);
                }
            }
        }
    };

    if (m <= CAPE)
        run([&](int j) { return eL[j - bbeg]; });
    else
        run([&](int j) { return csr_src[j]; });
}

extern "C" void kernel_launch(void* const* d_in, const int* in_sizes, int n_in,
                              void* d_out, int out_size, void* d_ws, size_t ws_size,
                              hipStream_t stream) {
    const float* x  = (const float*)d_in[0];
    const int*   ei = (const int*)d_in[1];
    const float* W1 = (const float*)d_in[2];
    const float* b1 = (const float*)d_in[3];
    const float* W2 = (const float*)d_in[4];
    const float* b2 = (const float*)d_in[5];
    float* out = (float*)d_out;

    const int N = in_sizes[0] / 128;
    const int E = in_sizes[1] / 2;
    const int* src = ei;
    const int* tgt = ei + E;

    const int nbk   = (N + 255) >> BSHIFT;               // buckets
    const int chunk = (((E + NB - 1) / NB) + 3) & ~3;    // ×4 for int4 alignment
    const int Mc    = nbk * NB;                          // counts length

    float* ws = (float*)d_ws;
    const size_t Np = (size_t)((N + 3) & ~3);
    float*  dinv    = ws;                            // Np
    int*    rowptr  = (int*)(ws + Np);               // Np+4
    int*    counts  = rowptr + Np + 4;               // MAXBK*NB (scanned in place)
    int*    bsum    = counts + MAXBK * NB;           // 128
    int*    csr_src = bsum + 128;                    // E
    int*    tmpP    = csr_src + E;                   // E packed (src<<8)|(tgt&255)
    ushort* h       = (ushort*)(tmpP + E);           // [8][N][16] bf16 (reused as h2 [4][N][16])
    ushort* h1      = h + (size_t)N * 128;           // [8][N][16] bf16
    ushort* h2      = h;

    const int nbc = (Mc + 1023) / 1024;

    // CSR build — no global atomics, no memsets (produces rowptr/dinv/csr_src)
    hist_kernel<<<NB, 256, 0, stream>>>(tgt, counts, E, chunk, nbk);
    scan_partial<<<nbc, 256, 0, stream>>>(counts, bsum, Mc);
    scan_final_counts<<<nbc, 256, 0, stream>>>(counts, bsum, Mc);
    bucket_scatter<<<NB, 256, 0, stream>>>(src, tgt, counts, tmpP, E, chunk, nbk);
    bucket_finish<<<nbk, 256, 0, stream>>>(tmpP, counts, rowptr, dinv, csr_src, N, E, nbk);

    const int ngb = (N + 63) / 64;   // gather grid: all-resident (~6 blocks/CU)

    // Layer 1: h' = dinv * (x@W1) slice-major; sliced gather; h1 = relu(...)
    gemm_mfma<128, float><<<(N + 63) / 64, 256, 0, stream>>>(x, W1, dinv, h, N);
    gather_sliced<128, true, true><<<ngb, 128, 0, stream>>>(
        h, rowptr, csr_src, dinv, b1, h1, N);

    // Layer 2: h2' = dinv * (h1@W2) slice-major; sliced gather -> out fp32
    gemm_mfma<64, ushort><<<(N + 63) / 64, 256, 0, stream>>>(h1, W2, dinv, h2, N);
    gather_sliced<64, false, false><<<ngb, 128, 0, stream>>>(
        h2, rowptr, csr_src, dinv, b2, out, N);
}

// Round 4
// 339.535 us; speedup vs baseline: 1.0109x; 1.0109x over previous
//
#include <hip/hip_runtime.h>

// ---------------------------------------------------------------------------
// 2-layer GCN forward, pull-mode, bf16 tables, MFMA GEMMs.
//
// R11: XCD-PARTITIONED feature-sliced gather (replaces R10's phased sweep).
// R10 post-mortem: phased slicing made fills compulsory-only but every XCD
// filled the WHOLE table (8 XCD x 25.6MB = 205MB ~ random's 271MB miss
// traffic -> no win) and the all-resident grid cut occupancy to 28% -> fill
// rate fell 3.7->2.1 TB/s -> 82->114us regression.  Fix: spatial partition.
// blockIdx&7 ~ XCD (round-robin dispatch heuristic; perf-only): slice s
// pinned to XCD s.  Block = 128 nodes x ONE 16-feature slice (3.2MB,
// permanently L2-resident per XCD, no duplication, no lockstep).  Full
// occupancy (256thr, 12.5K blocks, 28 VGPR).  Edge data reads become L2
// hits; fills drop to compulsory (~90MB vs 271MB).  4-deep ILP per
// lane-pair.  D=64 layer: slice = sl&3 (2 XCDs/slice, still 3.2MB/XCD).
//
// ws (4B units): dinv[Np] rowptr[Np+4] counts[MAXBK*NB] bsum[128]
//   csr_src[E] tmpP[E] | h ushort[N*128] (reused as h2) | h1 ushort[N*128]
// ---------------------------------------------------------------------------

typedef unsigned int uint;
typedef unsigned short ushort;
typedef __attribute__((ext_vector_type(8))) short bf16x8;
typedef __attribute__((ext_vector_type(8))) ushort u16x8;
typedef __attribute__((ext_vector_type(4))) float f32x4;

#define BSHIFT 8          // nodes per bucket = 256
#define MAXBK  512        // max buckets (N <= 131072)
#define NB     256        // hist/scatter blocks
#define CAP    8192       // LDS-staged edges per bucket (avg ~4096)

__device__ inline ushort f2bf(float f) {
    uint u = __float_as_uint(f);
    return (ushort)((u + 0x7fffu + ((u >> 16) & 1u)) >> 16);  // RNE
}
__device__ inline float bf_lo(uint u) { return __uint_as_float(u << 16); }
__device__ inline float bf_hi(uint u) { return __uint_as_float(u & 0xffff0000u); }

// ---- pass 1: per-block bucket histogram (LDS atomics only) ----
__global__ __launch_bounds__(256) void hist_kernel(const int* __restrict__ tgt,
                                                   int* __restrict__ counts,
                                                   int E, int chunk, int nbk) {
    __shared__ int hist[MAXBK];
    int t = threadIdx.x, b = blockIdx.x;
    for (int i = t; i < nbk; i += 256) hist[i] = 0;
    __syncthreads();
    int s = b * chunk, e = min(E, s + chunk);
    int i = s + t * 4;
    for (; i + 3 < e; i += 1024) {
        int4 tv = *(const int4*)&tgt[i];
        atomicAdd(&hist[tv.x >> BSHIFT], 1);
        atomicAdd(&hist[tv.y >> BSHIFT], 1);
        atomicAdd(&hist[tv.z >> BSHIFT], 1);
        atomicAdd(&hist[tv.w >> BSHIFT], 1);
    }
    if (i < e)
        for (int k = i; k < e; ++k) atomicAdd(&hist[tgt[k] >> BSHIFT], 1);
    __syncthreads();
    for (int i2 = t; i2 < nbk; i2 += 256) counts[i2 * NB + b] = hist[i2];
}

// ---- scan step 1: per-1024 partial sums of counts ----
__global__ __launch_bounds__(256) void scan_partial(const int* __restrict__ in,
                                                    int* __restrict__ bsum, int M) {
    int t = threadIdx.x, b = blockIdx.x;
    int base = b * 1024 + t * 4;
    int s = 0;
#pragma unroll
    for (int k = 0; k < 4; ++k) s += (base + k < M) ? in[base + k] : 0;
#pragma unroll
    for (int off = 32; off > 0; off >>= 1) s += __shfl_down(s, off, 64);
    __shared__ int ws[4];
    if ((t & 63) == 0) ws[t >> 6] = s;
    __syncthreads();
    if (t == 0) bsum[b] = ws[0] + ws[1] + ws[2] + ws[3];
}

// ---- scan step 2: exclusive scan of counts in place (bsum prefix fused) ----
__global__ __launch_bounds__(256) void scan_final_counts(int* __restrict__ counts,
                                                         const int* __restrict__ bsum,
                                                         int M) {
    int t = threadIdx.x, b = blockIdx.x;
    int lane = t & 63, wid = t >> 6;
    int p = 0;
    for (int i = t; i < b; i += 256) p += bsum[i];
#pragma unroll
    for (int off = 32; off > 0; off >>= 1) p += __shfl_down(p, off, 64);
    __shared__ int ps[4];
    if (lane == 0) ps[wid] = p;
    __syncthreads();
    int pre = ps[0] + ps[1] + ps[2] + ps[3];

    int base = b * 1024 + t * 4;
    int d[4];
#pragma unroll
    for (int k = 0; k < 4; ++k) d[k] = (base + k < M) ? counts[base + k] : 0;
    int tot = d[0] + d[1] + d[2] + d[3];
    int incl = tot;
#pragma unroll
    for (int off = 1; off < 64; off <<= 1) {
        int u = __shfl_up(incl, off, 64);
        if (lane >= off) incl += u;
    }
    __shared__ int wsum[4];
    if (lane == 63) wsum[wid] = incl;
    __syncthreads();
    int woff = 0;
    for (int w = 0; w < wid; ++w) woff += wsum[w];
    int run = incl - tot + woff + pre;
#pragma unroll
    for (int k = 0; k < 4; ++k) {
        if (base + k < M) counts[base + k] = run;
        run += d[k];
    }
}

// ---- pass 2: scatter edges into bucket-contiguous packed tmp ----
__global__ __launch_bounds__(256) void bucket_scatter(const int* __restrict__ src,
                                                      const int* __restrict__ tgt,
                                                      const int* __restrict__ offsets,
                                                      int* __restrict__ tmpP,
                                                      int E, int chunk, int nbk) {
    __shared__ int cur[MAXBK];
    int t = threadIdx.x, b = blockIdx.x;
    for (int i = t; i < nbk; i += 256) cur[i] = offsets[i * NB + b];
    __syncthreads();
    int s = b * chunk, e = min(E, s + chunk);
    int i = s + t * 4;
    for (; i + 3 < e; i += 1024) {
        int4 sv = *(const int4*)&src[i];
        int4 tv = *(const int4*)&tgt[i];
        int p0 = atomicAdd(&cur[tv.x >> BSHIFT], 1);
        tmpP[p0] = (sv.x << BSHIFT) | (tv.x & 255);
        int p1 = atomicAdd(&cur[tv.y >> BSHIFT], 1);
        tmpP[p1] = (sv.y << BSHIFT) | (tv.y & 255);
        int p2 = atomicAdd(&cur[tv.z >> BSHIFT], 1);
        tmpP[p2] = (sv.z << BSHIFT) | (tv.z & 255);
        int p3 = atomicAdd(&cur[tv.w >> BSHIFT], 1);
        tmpP[p3] = (sv.w << BSHIFT) | (tv.w & 255);
    }
    if (i < e) {
        for (int k = i; k < e; ++k) {
            int tg = tgt[k];
            int p = atomicAdd(&cur[tg >> BSHIFT], 1);
            tmpP[p] = (src[k] << BSHIFT) | (tg & 255);
        }
    }
}

// ---- pass 3 (fused): per-bucket deg count + scan + rowptr/dinv + csr fill ----
__global__ __launch_bounds__(256) void bucket_finish(const int* __restrict__ tmpP,
                                                     const int* __restrict__ offsets,
                                                     int* __restrict__ rowptr,
                                                     float* __restrict__ dinv,
                                                     int* __restrict__ csr_src,
                                                     int N, int E, int nbk) {
    __shared__ int stage[CAP];
    __shared__ int cnt[256];
    __shared__ int wsum[4];
    int t = threadIdx.x, b = blockIdx.x;
    cnt[t] = 0;
    __syncthreads();
    int s = offsets[b * NB];
    int e = (b + 1 < nbk) ? offsets[(b + 1) * NB] : E;
    int m = e - s;
    for (int i = t; i < m; i += 256) {
        int ed = tmpP[s + i];
        if (i < CAP) stage[i] = ed;
        atomicAdd(&cnt[ed & 255], 1);
    }
    __syncthreads();
    int lane = t & 63, wid = t >> 6;
    int d = cnt[t];
    int incl = d;
#pragma unroll
    for (int off = 1; off < 64; off <<= 1) {
        int u = __shfl_up(incl, off, 64);
        if (lane >= off) incl += u;
    }
    if (lane == 63) wsum[wid] = incl;
    __syncthreads();
    int woff = 0;
    for (int w = 0; w < wid; ++w) woff += wsum[w];
    int excl = s + incl - d + woff;
    int node = b * 256 + t;
    if (node < N) {
        rowptr[node] = excl;
        dinv[node] = rsqrtf((float)d + 1.0f);  // +1 self-loop
    }
    if (b == nbk - 1 && t == 255) rowptr[N] = E;
    cnt[t] = excl;  // reuse as cursor
    __syncthreads();
    for (int i = t; i < m; i += 256) {
        int ed = (i < CAP) ? stage[i] : tmpP[s + i];
        int p = atomicAdd(&cnt[ed & 255], 1);
        csr_src[p] = ed >> BSHIFT;
    }
}

// ---- MFMA GEMM: C(slice-major [M/16][N][16], bf16) = dinv[row]*(A @ W) ----
// block = 256 (4 waves), 64 rows/block; v_mfma_f32_16x16x32_bf16.
// AT = float: A row-major [N][128] fp32 (convert in flight).
// AT = ushort: A slice-major [128/16][N][16] bf16 (gather-table layout).
template <int M, typename AT>
__global__ __launch_bounds__(256) void gemm_mfma(const AT* __restrict__ A,
                                                 const float* __restrict__ W,
                                                 const float* __restrict__ dinv,
                                                 ushort* __restrict__ C, int N) {
    constexpr int WTS = 136;           // padded row stride (bf16)
    __shared__ ushort WT[M * WTS];     // WT[n][k] = W[k][n]
    const int tid = threadIdx.x;
    for (int i = tid; i < 128 * (M / 4); i += 256) {
        int k = i / (M / 4);
        int n0 = (i % (M / 4)) * 4;
        float4 w = *(const float4*)&W[k * M + n0];
        WT[(n0 + 0) * WTS + k] = f2bf(w.x);
        WT[(n0 + 1) * WTS + k] = f2bf(w.y);
        WT[(n0 + 2) * WTS + k] = f2bf(w.z);
        WT[(n0 + 3) * WTS + k] = f2bf(w.w);
    }
    __syncthreads();

    const int wv = tid >> 6, lane = tid & 63;
    const int quad = lane >> 4, mrow = lane & 15;
    int arow_i = blockIdx.x * 64 + wv * 16 + mrow;
    if (arow_i >= N) arow_i = N - 1;   // clamp loads; stores guarded

    f32x4 acc[M / 16];
#pragma unroll
    for (int t = 0; t < M / 16; ++t) acc[t] = (f32x4){0.f, 0.f, 0.f, 0.f};

#pragma unroll
    for (int ks = 0; ks < 4; ++ks) {
        const int k0 = ks * 32 + quad * 8;
        bf16x8 af;
        if constexpr (sizeof(AT) == 4) {
            const float* arow = (const float*)A + (size_t)arow_i * 128;
            float4 a0 = *(const float4*)&arow[k0];
            float4 a1 = *(const float4*)&arow[k0 + 4];
            af[0] = (short)f2bf(a0.x); af[1] = (short)f2bf(a0.y);
            af[2] = (short)f2bf(a0.z); af[3] = (short)f2bf(a0.w);
            af[4] = (short)f2bf(a1.x); af[5] = (short)f2bf(a1.y);
            af[6] = (short)f2bf(a1.z); af[7] = (short)f2bf(a1.w);
        } else {
            // slice-major: features k0..k0+7 live in slice k0>>4 at offset k0&15
            af = *(const bf16x8*)((const ushort*)A +
                                  ((size_t)(k0 >> 4) * N + arow_i) * 16 + (k0 & 15));
        }
#pragma unroll
        for (int t = 0; t < M / 16; ++t) {
            int n = t * 16 + mrow;
            bf16x8 bfr = *(const bf16x8*)&WT[n * WTS + k0];
            acc[t] = __builtin_amdgcn_mfma_f32_16x16x32_bf16(af, bfr, acc[t], 0, 0, 0);
        }
    }

    const int orow0 = blockIdx.x * 64 + wv * 16 + quad * 4;
#pragma unroll
    for (int r = 0; r < 4; ++r) {
        int orow = orow0 + r;
        if (orow < N) {
            float dv = dinv[orow];   // pre-scale row into the gather table
#pragma unroll
            for (int t = 0; t < M / 16; ++t)
                C[((size_t)t * N + orow) * 16 + mrow] = f2bf(dv * acc[t][r]);
        }
    }
}

// ---- XCD-partitioned feature-sliced gather ----
// h slice-major [D/16][N][16] bf16 (pre-scaled by dinv[src]).  Grid =
// nodeblocks x 8; sl = blockIdx&7 ~ XCD id (round-robin dispatch heuristic,
// perf-only), slice s = sl & (NS-1) pinned to that XCD -> 3.2MB working set
// permanently L2-resident, no cross-XCD duplication.  Block = 256 thr = 128
// nodes, lane-pair per node (q = lane&1 covers 8 of the 16 slice features).
// Edge list staged in LDS (single pass).  4-deep ILP.
// out[v] = dinv[v]*(sum_e h'[src] + h'[v]) + b
template <int D, bool RELU, bool OUTBF>
__global__ __launch_bounds__(256) void gather_part(
    const ushort* __restrict__ h, const int* __restrict__ rowptr,
    const int* __restrict__ csr_src, const float* __restrict__ dinv,
    const float* __restrict__ bias, void* __restrict__ outv, int N) {
    constexpr int NS = D / 16;     // feature slices (8 or 4)
    constexpr int CAPE = 4096;     // LDS-staged edges per block (avg ~2048)
    __shared__ int eL[CAPE];
    const int tid = threadIdx.x;
    const int sl = blockIdx.x & 7;         // ~ XCD id
    const int s  = sl & (NS - 1);          // slice owned by this XCD
    const int nb = blockIdx.x >> 3;
    const int base = nb * 128;
    const int bbeg = rowptr[base];
    const int bend = rowptr[min(base + 128, N)];
    const int m = bend - bbeg;
    for (int i = tid; i < m && i < CAPE; i += 256) eL[i] = csr_src[bbeg + i];
    __syncthreads();

    const int node = base + (tid >> 1);
    if (node >= N) return;                 // no barriers after this point
    const int q = tid & 1;
    const int qoff = q * 8;
    const int beg = rowptr[node], end = rowptr[node + 1];
    const float di = dinv[node];
    const ushort* hs = h + (size_t)s * N * 16;

    float acc[8] = {};
    auto acc8 = [&](uint4 v) {
        acc[0] += bf_lo(v.x); acc[1] += bf_hi(v.x);
        acc[2] += bf_lo(v.y); acc[3] += bf_hi(v.y);
        acc[4] += bf_lo(v.z); acc[5] += bf_hi(v.z);
        acc[6] += bf_lo(v.w); acc[7] += bf_hi(v.w);
    };

    auto body = [&](auto LD) {
        int j = beg;
        for (; j + 3 < end; j += 4) {      // 4 independent loads in flight
            int s0 = LD(j), s1 = LD(j + 1), s2 = LD(j + 2), s3 = LD(j + 3);
            uint4 v0 = *(const uint4*)&hs[(size_t)s0 * 16 + qoff];
            uint4 v1 = *(const uint4*)&hs[(size_t)s1 * 16 + qoff];
            uint4 v2 = *(const uint4*)&hs[(size_t)s2 * 16 + qoff];
            uint4 v3 = *(const uint4*)&hs[(size_t)s3 * 16 + qoff];
            acc8(v0); acc8(v1); acc8(v2); acc8(v3);
        }
        for (; j < end; ++j) {
            int s0 = LD(j);
            acc8(*(const uint4*)&hs[(size_t)s0 * 16 + qoff]);
        }
    };
    if (m <= CAPE)
        body([&](int j) { return eL[j - bbeg]; });
    else
        body([&](int j) { return csr_src[j]; });

    // self-loop: + h'[node]
    acc8(*(const uint4*)&hs[(size_t)node * 16 + qoff]);

    float4 b0 = *(const float4*)&bias[s * 16 + qoff];
    float4 b1 = *(const float4*)&bias[s * 16 + qoff + 4];
    float r[8] = {di * acc[0] + b0.x, di * acc[1] + b0.y,
                  di * acc[2] + b0.z, di * acc[3] + b0.w,
                  di * acc[4] + b1.x, di * acc[5] + b1.y,
                  di * acc[6] + b1.z, di * acc[7] + b1.w};
    if (RELU) {
#pragma unroll
        for (int k = 0; k < 8; ++k) r[k] = fmaxf(r[k], 0.0f);
    }
    if constexpr (OUTBF) {
        ushort* out = (ushort*)outv;       // slice-major bf16
        u16x8 o;
#pragma unroll
        for (int k = 0; k < 8; ++k) o[k] = f2bf(r[k]);
        *(u16x8*)&out[((size_t)s * N + node) * 16 + qoff] = o;
    } else {
        float* out = (float*)outv;         // row-major fp32
        *(float4*)&out[(size_t)node * D + s * 16 + qoff] =
            make_float4(r[0], r[1], r[2], r[3]);
        *(float4*)&out[(size_t)node * D + s * 16 + qoff + 4] =
            make_float4(r[4], r[5], r[6], r[7]);
    }
}

extern "C" void kernel_launch(void* const* d_in, const int* in_sizes, int n_in,
                              void* d_out, int out_size, void* d_ws, size_t ws_size,
                              hipStream_t stream) {
    const float* x  = (const float*)d_in[0];
    const int*   ei = (const int*)d_in[1];
    const float* W1 = (const float*)d_in[2];
    const float* b1 = (const float*)d_in[3];
    const float* W2 = (const float*)d_in[4];
    const float* b2 = (const float*)d_in[5];
    float* out = (float*)d_out;

    const int N = in_sizes[0] / 128;
    const int E = in_sizes[1] / 2;
    const int* src = ei;
    const int* tgt = ei + E;

    const int nbk   = (N + 255) >> BSHIFT;               // buckets
    const int chunk = (((E + NB - 1) / NB) + 3) & ~3;    // ×4 for int4 alignment
    const int Mc    = nbk * NB;                          // counts length

    float* ws = (float*)d_ws;
    const size_t Np = (size_t)((N + 3) & ~3);
    float*  dinv    = ws;                            // Np
    int*    rowptr  = (int*)(ws + Np);               // Np+4
    int*    counts  = rowptr + Np + 4;               // MAXBK*NB (scanned in place)
    int*    bsum    = counts + MAXBK * NB;           // 128
    int*    csr_src = bsum + 128;                    // E
    int*    tmpP    = csr_src + E;                   // E packed (src<<8)|(tgt&255)
    ushort* h       = (ushort*)(tmpP + E);           // [8][N][16] bf16 (reused as h2 [4][N][16])
    ushort* h1      = h + (size_t)N * 128;           // [8][N][16] bf16
    ushort* h2      = h;

    const int nbc = (Mc + 1023) / 1024;

    // CSR build — no global atomics, no memsets (produces rowptr/dinv/csr_src)
    hist_kernel<<<NB, 256, 0, stream>>>(tgt, counts, E, chunk, nbk);
    scan_partial<<<nbc, 256, 0, stream>>>(counts, bsum, Mc);
    scan_final_counts<<<nbc, 256, 0, stream>>>(counts, bsum, Mc);
    bucket_scatter<<<NB, 256, 0, stream>>>(src, tgt, counts, tmpP, E, chunk, nbk);
    bucket_finish<<<nbk, 256, 0, stream>>>(tmpP, counts, rowptr, dinv, csr_src, N, E, nbk);

    const int ngb = (N + 127) / 128;   // node-blocks (128 nodes each)

    // Layer 1: h' = dinv * (x@W1) slice-major; XCD-partitioned gather; h1 = relu
    gemm_mfma<128, float><<<(N + 63) / 64, 256, 0, stream>>>(x, W1, dinv, h, N);
    gather_part<128, true, true><<<ngb * 8, 256, 0, stream>>>(
        h, rowptr, csr_src, dinv, b1, h1, N);

    // Layer 2: h2' = dinv * (h1@W2) slice-major; partitioned gather -> out fp32
    gemm_mfma<64, ushort><<<(N + 63) / 64, 256, 0, stream>>>(h1, W2, dinv, h2, N);
    gather_part<64, false, false><<<ngb * 8, 256, 0, stream>>>(
        h2, rowptr, csr_src, dinv, b2, out, N);
}

// Round 5
// 309.475 us; speedup vs baseline: 1.1091x; 1.0971x over previous
//
#include <hip/hip_runtime.h>

// ---------------------------------------------------------------------------
// 2-layer GCN forward, pull-mode, bf16 tables, MFMA GEMMs.
//
// R12: revert to R9 structure (verified 309us; R10/R11 slicing experiments
// regressed -- post-mortem: per-edge cost ~32 CU-cyc invariant across
// designs, t ~ 8cyc*visits + 0.09cyc/B*bytes; 32B slice reads suffer 4x
// L2-line amplification that cancels residency gains; 256B/edge contiguous
// is the minimal-waste shape).  This round: (a) gemm blocks do 128 rows
// (2 halves share one LDS W^T stage -> W re-read traffic halved, grid
// halved); (b) gather main loop = unmasked full groups + one masked tail
// (dummy slots read row 0, always cache-hot; mask VALU out of hot loop).
//
// ws (4B units): dinv[Np] rowptr[Np+4] counts[MAXBK*NB] bsum[128]
//   csr_src[E] tmpP[E] | h ushort[N*128] (reused as h2 ushort[N*64])
//   | h1 ushort[N*128]
// ---------------------------------------------------------------------------

typedef unsigned int uint;
typedef unsigned short ushort;
typedef __attribute__((ext_vector_type(8))) short bf16x8;
typedef __attribute__((ext_vector_type(8))) ushort u16x8;
typedef __attribute__((ext_vector_type(4))) float f32x4;

#define BSHIFT 8          // nodes per bucket = 256
#define MAXBK  512        // max buckets (N <= 131072)
#define NB     256        // hist/scatter blocks
#define CAP    8192       // LDS-staged edges per bucket (avg ~4096)

__device__ inline ushort f2bf(float f) {
    uint u = __float_as_uint(f);
    return (ushort)((u + 0x7fffu + ((u >> 16) & 1u)) >> 16);  // RNE
}
__device__ inline float bf_lo(uint u) { return __uint_as_float(u << 16); }
__device__ inline float bf_hi(uint u) { return __uint_as_float(u & 0xffff0000u); }

// ---- pass 1: per-block bucket histogram (LDS atomics only) ----
__global__ __launch_bounds__(256) void hist_kernel(const int* __restrict__ tgt,
                                                   int* __restrict__ counts,
                                                   int E, int chunk, int nbk) {
    __shared__ int hist[MAXBK];
    int t = threadIdx.x, b = blockIdx.x;
    for (int i = t; i < nbk; i += 256) hist[i] = 0;
    __syncthreads();
    int s = b * chunk, e = min(E, s + chunk);
    int i = s + t * 4;
    for (; i + 3 < e; i += 1024) {
        int4 tv = *(const int4*)&tgt[i];
        atomicAdd(&hist[tv.x >> BSHIFT], 1);
        atomicAdd(&hist[tv.y >> BSHIFT], 1);
        atomicAdd(&hist[tv.z >> BSHIFT], 1);
        atomicAdd(&hist[tv.w >> BSHIFT], 1);
    }
    if (i < e)
        for (int k = i; k < e; ++k) atomicAdd(&hist[tgt[k] >> BSHIFT], 1);
    __syncthreads();
    for (int i2 = t; i2 < nbk; i2 += 256) counts[i2 * NB + b] = hist[i2];
}

// ---- scan step 1: per-1024 partial sums of counts ----
__global__ __launch_bounds__(256) void scan_partial(const int* __restrict__ in,
                                                    int* __restrict__ bsum, int M) {
    int t = threadIdx.x, b = blockIdx.x;
    int base = b * 1024 + t * 4;
    int s = 0;
#pragma unroll
    for (int k = 0; k < 4; ++k) s += (base + k < M) ? in[base + k] : 0;
#pragma unroll
    for (int off = 32; off > 0; off >>= 1) s += __shfl_down(s, off, 64);
    __shared__ int ws[4];
    if ((t & 63) == 0) ws[t >> 6] = s;
    __syncthreads();
    if (t == 0) bsum[b] = ws[0] + ws[1] + ws[2] + ws[3];
}

// ---- scan step 2: exclusive scan of counts in place (bsum prefix fused) ----
__global__ __launch_bounds__(256) void scan_final_counts(int* __restrict__ counts,
                                                         const int* __restrict__ bsum,
                                                         int M) {
    int t = threadIdx.x, b = blockIdx.x;
    int lane = t & 63, wid = t >> 6;
    int p = 0;
    for (int i = t; i < b; i += 256) p += bsum[i];
#pragma unroll
    for (int off = 32; off > 0; off >>= 1) p += __shfl_down(p, off, 64);
    __shared__ int ps[4];
    if (lane == 0) ps[wid] = p;
    __syncthreads();
    int pre = ps[0] + ps[1] + ps[2] + ps[3];

    int base = b * 1024 + t * 4;
    int d[4];
#pragma unroll
    for (int k = 0; k < 4; ++k) d[k] = (base + k < M) ? counts[base + k] : 0;
    int tot = d[0] + d[1] + d[2] + d[3];
    int incl = tot;
#pragma unroll
    for (int off = 1; off < 64; off <<= 1) {
        int u = __shfl_up(incl, off, 64);
        if (lane >= off) incl += u;
    }
    __shared__ int wsum[4];
    if (lane == 63) wsum[wid] = incl;
    __syncthreads();
    int woff = 0;
    for (int w = 0; w < wid; ++w) woff += wsum[w];
    int run = incl - tot + woff + pre;
#pragma unroll
    for (int k = 0; k < 4; ++k) {
        if (base + k < M) counts[base + k] = run;
        run += d[k];
    }
}

// ---- pass 2: scatter edges into bucket-contiguous packed tmp ----
__global__ __launch_bounds__(256) void bucket_scatter(const int* __restrict__ src,
                                                      const int* __restrict__ tgt,
                                                      const int* __restrict__ offsets,
                                                      int* __restrict__ tmpP,
                                                      int E, int chunk, int nbk) {
    __shared__ int cur[MAXBK];
    int t = threadIdx.x, b = blockIdx.x;
    for (int i = t; i < nbk; i += 256) cur[i] = offsets[i * NB + b];
    __syncthreads();
    int s = b * chunk, e = min(E, s + chunk);
    int i = s + t * 4;
    for (; i + 3 < e; i += 1024) {
        int4 sv = *(const int4*)&src[i];
        int4 tv = *(const int4*)&tgt[i];
        int p0 = atomicAdd(&cur[tv.x >> BSHIFT], 1);
        tmpP[p0] = (sv.x << BSHIFT) | (tv.x & 255);
        int p1 = atomicAdd(&cur[tv.y >> BSHIFT], 1);
        tmpP[p1] = (sv.y << BSHIFT) | (tv.y & 255);
        int p2 = atomicAdd(&cur[tv.z >> BSHIFT], 1);
        tmpP[p2] = (sv.z << BSHIFT) | (tv.z & 255);
        int p3 = atomicAdd(&cur[tv.w >> BSHIFT], 1);
        tmpP[p3] = (sv.w << BSHIFT) | (tv.w & 255);
    }
    if (i < e) {
        for (int k = i; k < e; ++k) {
            int tg = tgt[k];
            int p = atomicAdd(&cur[tg >> BSHIFT], 1);
            tmpP[p] = (src[k] << BSHIFT) | (tg & 255);
        }
    }
}

// ---- pass 3 (fused): per-bucket deg count + scan + rowptr/dinv + csr fill ----
__global__ __launch_bounds__(256) void bucket_finish(const int* __restrict__ tmpP,
                                                     const int* __restrict__ offsets,
                                                     int* __restrict__ rowptr,
                                                     float* __restrict__ dinv,
                                                     int* __restrict__ csr_src,
                                                     int N, int E, int nbk) {
    __shared__ int stage[CAP];
    __shared__ int cnt[256];
    __shared__ int wsum[4];
    int t = threadIdx.x, b = blockIdx.x;
    cnt[t] = 0;
    __syncthreads();
    int s = offsets[b * NB];
    int e = (b + 1 < nbk) ? offsets[(b + 1) * NB] : E;
    int m = e - s;
    for (int i = t; i < m; i += 256) {
        int ed = tmpP[s + i];
        if (i < CAP) stage[i] = ed;
        atomicAdd(&cnt[ed & 255], 1);
    }
    __syncthreads();
    int lane = t & 63, wid = t >> 6;
    int d = cnt[t];
    int incl = d;
#pragma unroll
    for (int off = 1; off < 64; off <<= 1) {
        int u = __shfl_up(incl, off, 64);
        if (lane >= off) incl += u;
    }
    if (lane == 63) wsum[wid] = incl;
    __syncthreads();
    int woff = 0;
    for (int w = 0; w < wid; ++w) woff += wsum[w];
    int excl = s + incl - d + woff;
    int node = b * 256 + t;
    if (node < N) {
        rowptr[node] = excl;
        dinv[node] = rsqrtf((float)d + 1.0f);  // +1 self-loop
    }
    if (b == nbk - 1 && t == 255) rowptr[N] = E;
    cnt[t] = excl;  // reuse as cursor
    __syncthreads();
    for (int i = t; i < m; i += 256) {
        int ed = (i < CAP) ? stage[i] : tmpP[s + i];
        int p = atomicAdd(&cnt[ed & 255], 1);
        csr_src[p] = ed >> BSHIFT;
    }
}

// ---- MFMA GEMM: C[N,M](bf16) = dinv[row] * (A[N,128] @ W[128,M]) ----
// block = 256 (4 waves), 128 rows/block in two 64-row halves sharing one
// LDS-staged W^T (halves W re-read traffic vs 64-row blocks).
// AT = float (convert in-flight) or ushort (bf16, load direct).
template <int M, typename AT>
__global__ __launch_bounds__(256) void gemm_mfma(const AT* __restrict__ A,
                                                 const float* __restrict__ W,
                                                 const float* __restrict__ dinv,
                                                 ushort* __restrict__ C, int N) {
    constexpr int WTS = 136;           // padded row stride (bf16)
    __shared__ ushort WT[M * WTS];     // WT[n][k] = W[k][n]
    const int tid = threadIdx.x;
    for (int i = tid; i < 128 * (M / 4); i += 256) {
        int k = i / (M / 4);
        int n0 = (i % (M / 4)) * 4;
        float4 w = *(const float4*)&W[k * M + n0];
        WT[(n0 + 0) * WTS + k] = f2bf(w.x);
        WT[(n0 + 1) * WTS + k] = f2bf(w.y);
        WT[(n0 + 2) * WTS + k] = f2bf(w.z);
        WT[(n0 + 3) * WTS + k] = f2bf(w.w);
    }
    __syncthreads();

    const int wv = tid >> 6, lane = tid & 63;
    const int quad = lane >> 4, mrow = lane & 15;
    const int r0 = blockIdx.x * 128 + wv * 16 + mrow;   // half 0 row
    const int r1 = r0 + 64;                              // half 1 row
    const int a0i = min(r0, N - 1);    // clamp loads; stores guarded
    const int a1i = min(r1, N - 1);

    f32x4 acc0[M / 16], acc1[M / 16];
#pragma unroll
    for (int t = 0; t < M / 16; ++t) {
        acc0[t] = (f32x4){0.f, 0.f, 0.f, 0.f};
        acc1[t] = (f32x4){0.f, 0.f, 0.f, 0.f};
    }

#pragma unroll
    for (int ks = 0; ks < 4; ++ks) {
        const int k0 = ks * 32 + quad * 8;
        bf16x8 af0, af1;
        if constexpr (sizeof(AT) == 4) {
            const float* ar0 = (const float*)A + (size_t)a0i * 128;
            const float* ar1 = (const float*)A + (size_t)a1i * 128;
            float4 x0 = *(const float4*)&ar0[k0];
            float4 y0 = *(const float4*)&ar0[k0 + 4];
            float4 x1 = *(const float4*)&ar1[k0];
            float4 y1 = *(const float4*)&ar1[k0 + 4];
            af0[0] = (short)f2bf(x0.x); af0[1] = (short)f2bf(x0.y);
            af0[2] = (short)f2bf(x0.z); af0[3] = (short)f2bf(x0.w);
            af0[4] = (short)f2bf(y0.x); af0[5] = (short)f2bf(y0.y);
            af0[6] = (short)f2bf(y0.z); af0[7] = (short)f2bf(y0.w);
            af1[0] = (short)f2bf(x1.x); af1[1] = (short)f2bf(x1.y);
            af1[2] = (short)f2bf(x1.z); af1[3] = (short)f2bf(x1.w);
            af1[4] = (short)f2bf(y1.x); af1[5] = (short)f2bf(y1.y);
            af1[6] = (short)f2bf(y1.z); af1[7] = (short)f2bf(y1.w);
        } else {
            af0 = *(const bf16x8*)((const ushort*)A + (size_t)a0i * 128 + k0);
            af1 = *(const bf16x8*)((const ushort*)A + (size_t)a1i * 128 + k0);
        }
#pragma unroll
        for (int t = 0; t < M / 16; ++t) {
            bf16x8 bfr = *(const bf16x8*)&WT[(t * 16 + mrow) * WTS + k0];
            acc0[t] = __builtin_amdgcn_mfma_f32_16x16x32_bf16(af0, bfr, acc0[t], 0, 0, 0);
            acc1[t] = __builtin_amdgcn_mfma_f32_16x16x32_bf16(af1, bfr, acc1[t], 0, 0, 0);
        }
    }

    const int ob0 = blockIdx.x * 128 + wv * 16 + quad * 4;
#pragma unroll
    for (int r = 0; r < 4; ++r) {
        int o0 = ob0 + r;
        if (o0 < N) {
            float dv = dinv[o0];   // pre-scale row into the gather table
#pragma unroll
            for (int t = 0; t < M / 16; ++t)
                C[(size_t)o0 * M + t * 16 + mrow] = f2bf(dv * acc0[t][r]);
        }
        int o1 = ob0 + 64 + r;
        if (o1 < N) {
            float dv = dinv[o1];
#pragma unroll
            for (int t = 0; t < M / 16; ++t)
                C[(size_t)o1 * M + t * 16 + mrow] = f2bf(dv * acc1[t][r]);
        }
    }
}

// ---- pull gather over pre-scaled table.  Q=D/8 lanes/row, G=64/Q slots.
// out[v] = dinv[v]*(sum h'[src] + h'[v]) + b;  no per-edge dinv load.
// Main loop: full unmasked 2G-edge groups (2 chains in flight); single
// masked tail group (dummy slots read row 0 -- always cache-hot).
template <int D, bool RELU, bool OUTBF>
__global__ __launch_bounds__(256) void gather_kernel(
    const ushort* __restrict__ h, const int* __restrict__ rowptr,
    const int* __restrict__ csr_src, const float* __restrict__ dinv,
    const float* __restrict__ bias, void* __restrict__ outv, int N) {
    constexpr int Q = D / 8;   // lanes covering one row (16B bf16x8 per lane)
    constexpr int G = 64 / Q;  // concurrent edge slots per wave
    const int wid = threadIdx.x >> 6, lane = threadIdx.x & 63;
    const int node = blockIdx.x * 4 + wid;
    if (node >= N) return;
    const int g = lane / Q, q = lane % Q;
    const int qoff = q * 8;
    const int beg = rowptr[node], end = rowptr[node + 1];
    float acc[8] = {};

    int j = beg;
    for (; j + 2 * G <= end; j += 2 * G) {  // full groups, no masks
        int s0 = csr_src[j + g];
        int s1 = csr_src[j + G + g];
        uint4 va = *(const uint4*)&h[(size_t)s0 * D + qoff];
        uint4 vb = *(const uint4*)&h[(size_t)s1 * D + qoff];
        acc[0] += bf_lo(va.x); acc[1] += bf_hi(va.x);
        acc[2] += bf_lo(va.y); acc[3] += bf_hi(va.y);
        acc[4] += bf_lo(va.z); acc[5] += bf_hi(va.z);
        acc[6] += bf_lo(va.w); acc[7] += bf_hi(va.w);
        acc[0] += bf_lo(vb.x); acc[1] += bf_hi(vb.x);
        acc[2] += bf_lo(vb.y); acc[3] += bf_hi(vb.y);
        acc[4] += bf_lo(vb.z); acc[5] += bf_hi(vb.z);
        acc[6] += bf_lo(vb.w); acc[7] += bf_hi(vb.w);
    }
    if (j < end) {                          // one masked tail group
        int e0 = j + g, e1 = j + G + g;
        bool v0 = e0 < end, v1 = e1 < end;
        int s0 = v0 ? csr_src[e0] : 0;      // dummy -> row 0 (hot)
        int s1 = v1 ? csr_src[e1] : 0;
        float m0 = v0 ? 1.0f : 0.0f;
        float m1 = v1 ? 1.0f : 0.0f;
        uint4 va = *(const uint4*)&h[(size_t)s0 * D + qoff];
        uint4 vb = *(const uint4*)&h[(size_t)s1 * D + qoff];
        acc[0] += m0 * bf_lo(va.x); acc[1] += m0 * bf_hi(va.x);
        acc[2] += m0 * bf_lo(va.y); acc[3] += m0 * bf_hi(va.y);
        acc[4] += m0 * bf_lo(va.z); acc[5] += m0 * bf_hi(va.z);
        acc[6] += m0 * bf_lo(va.w); acc[7] += m0 * bf_hi(va.w);
        acc[0] += m1 * bf_lo(vb.x); acc[1] += m1 * bf_hi(vb.x);
        acc[2] += m1 * bf_lo(vb.y); acc[3] += m1 * bf_hi(vb.y);
        acc[4] += m1 * bf_lo(vb.z); acc[5] += m1 * bf_hi(vb.z);
        acc[6] += m1 * bf_lo(vb.w); acc[7] += m1 * bf_hi(vb.w);
    }
#pragma unroll
    for (int m2 = Q; m2 < 64; m2 <<= 1)
#pragma unroll
        for (int k = 0; k < 8; ++k) acc[k] += __shfl_xor(acc[k], m2, 64);

    {   // self-loop: + h'[node]
        uint4 hv = *(const uint4*)&h[(size_t)node * D + qoff];
        acc[0] += bf_lo(hv.x); acc[1] += bf_hi(hv.x);
        acc[2] += bf_lo(hv.y); acc[3] += bf_hi(hv.y);
        acc[4] += bf_lo(hv.z); acc[5] += bf_hi(hv.z);
        acc[6] += bf_lo(hv.w); acc[7] += bf_hi(hv.w);
    }
    if (g == 0) {
        const float di = dinv[node];
        float4 b0 = *(const float4*)&bias[qoff];
        float4 b1 = *(const float4*)&bias[qoff + 4];
        float r[8] = {di * acc[0] + b0.x, di * acc[1] + b0.y,
                      di * acc[2] + b0.z, di * acc[3] + b0.w,
                      di * acc[4] + b1.x, di * acc[5] + b1.y,
                      di * acc[6] + b1.z, di * acc[7] + b1.w};
        if (RELU) {
#pragma unroll
            for (int k = 0; k < 8; ++k) r[k] = fmaxf(r[k], 0.0f);
        }
        if constexpr (OUTBF) {
            ushort* out = (ushort*)outv;
            u16x8 o;
#pragma unroll
            for (int k = 0; k < 8; ++k) o[k] = f2bf(r[k]);
            *(u16x8*)&out[(size_t)node * D + qoff] = o;
        } else {
            float* out = (float*)outv;
            *(float4*)&out[(size_t)node * D + qoff]     = make_float4(r[0], r[1], r[2], r[3]);
            *(float4*)&out[(size_t)node * D + qoff + 4] = make_float4(r[4], r[5], r[6], r[7]);
        }
    }
}

extern "C" void kernel_launch(void* const* d_in, const int* in_sizes, int n_in,
                              void* d_out, int out_size, void* d_ws, size_t ws_size,
                              hipStream_t stream) {
    const float* x  = (const float*)d_in[0];
    const int*   ei = (const int*)d_in[1];
    const float* W1 = (const float*)d_in[2];
    const float* b1 = (const float*)d_in[3];
    const float* W2 = (const float*)d_in[4];
    const float* b2 = (const float*)d_in[5];
    float* out = (float*)d_out;

    const int N = in_sizes[0] / 128;
    const int E = in_sizes[1] / 2;
    const int* src = ei;
    const int* tgt = ei + E;

    const int nbk   = (N + 255) >> BSHIFT;               // buckets
    const int chunk = (((E + NB - 1) / NB) + 3) & ~3;    // ×4 for int4 alignment
    const int Mc    = nbk * NB;                          // counts length

    float* ws = (float*)d_ws;
    const size_t Np = (size_t)((N + 3) & ~3);
    float*  dinv    = ws;                            // Np
    int*    rowptr  = (int*)(ws + Np);               // Np+4
    int*    counts  = rowptr + Np + 4;               // MAXBK*NB (scanned in place)
    int*    bsum    = counts + MAXBK * NB;           // 128
    int*    csr_src = bsum + 128;                    // E
    int*    tmpP    = csr_src + E;                   // E packed (src<<8)|(tgt&255)
    ushort* h       = (ushort*)(tmpP + E);           // N*128 bf16 (reused as h2)
    ushort* h1      = h + (size_t)N * 128;           // N*128 bf16
    ushort* h2      = h;

    const int nbc = (Mc + 1023) / 1024;

    // CSR build — no global atomics, no memsets (produces rowptr/dinv/csr_src)
    hist_kernel<<<NB, 256, 0, stream>>>(tgt, counts, E, chunk, nbk);
    scan_partial<<<nbc, 256, 0, stream>>>(counts, bsum, Mc);
    scan_final_counts<<<nbc, 256, 0, stream>>>(counts, bsum, Mc);
    bucket_scatter<<<NB, 256, 0, stream>>>(src, tgt, counts, tmpP, E, chunk, nbk);
    bucket_finish<<<nbk, 256, 0, stream>>>(tmpP, counts, rowptr, dinv, csr_src, N, E, nbk);

    // Layer 1: h' = dinv * (x@W1)  (scaled in epilogue); gather; h1 = relu(...)
    gemm_mfma<128, float><<<(N + 127) / 128, 256, 0, stream>>>(x, W1, dinv, h, N);
    gather_kernel<128, true, true><<<(N + 3) / 4, 256, 0, stream>>>(
        h, rowptr, csr_src, dinv, b1, h1, N);

    // Layer 2: h2' = dinv * (h1@W2); gather -> out fp32
    gemm_mfma<64, ushort><<<(N + 127) / 128, 256, 0, stream>>>(h1, W2, dinv, h2, N);
    gather_kernel<64, false, false><<<(N + 3) / 4, 256, 0, stream>>>(
        h2, rowptr, csr_src, dinv, b2, out, N);
}